// Round 11
// baseline (201.287 us; speedup 1.0000x reference)
//
#include <hip/hip_runtime.h>
#include <math.h>

#define BATCH 256
#define SEQ 100
#define DMODEL 256
#define DI 512
#define DID 512
#define NST 16
#define DTRANK 16
#define DCONV 4
#define NLAYERS 3

// workspace layout (floats)
#define W2_OFF 0              // 8*1024
#define B2_OFF 8192           // 1024
#define WTJ_OFF 9216          // 8*512*6 j-grouped tight xproj: [jg][c][6]
#define CWT_OFF 33792         // 4*512 transposed conv_w
#define FLAG_OFF 35840        // 2 ints
#define PROJ_OFF 35848        // 25600*48
#define SILUZ_OFF 1264648     // 256*512
#define Y_OFF 1395720         // 256*512
#define MOWT_OFF 1526792      // 256*512 m_out_w transposed [j][c]

__device__ __forceinline__ float silu_f(float x) { return x / (1.0f + __expf(-x)); }

#define DPP_ADD(v, ctrl, rmask) \
    v += __int_as_float(__builtin_amdgcn_update_dpp(0, __float_as_int(v), ctrl, rmask, 0xF, false))

__device__ __forceinline__ float wave64_sum(float v) {
    DPP_ADD(v, 0xB1, 0xF);
    DPP_ADD(v, 0x4E, 0xF);
    DPP_ADD(v, 0x141, 0xF);
    DPP_ADD(v, 0x140, 0xF);
    DPP_ADD(v, 0x142, 0xA);
    DPP_ADD(v, 0x143, 0xC);
    return v;
}

typedef float sf16 __attribute__((ext_vector_type(16)));
typedef float sf8 __attribute__((ext_vector_type(8)));

__device__ __forceinline__ int rfl(int v) { return __builtin_amdgcn_readfirstlane(v); }

#define SL2(dA, dB, base, offA, offB)                    \
    asm volatile("s_load_dwordx16 %0, %2, %3\n\t"        \
                 "s_load_dwordx16 %1, %2, %4"            \
                 : "=&s"(dA), "=&s"(dB)                  \
                 : "s"(base), "s"(offA), "s"(offB))
#define SLX(dX, base, off) \
    asm volatile("s_load_dwordx8 %0, %1, %2" : "=&s"(dX) : "s"(base), "s"(off))
#define SLC(dC, base, off) \
    asm volatile("s_load_dwordx16 %0, %1, %2" : "=&s"(dC) : "s"(base), "s"(off))
#define SL_WAIT()                                          \
    do {                                                   \
        asm volatile("s_waitcnt lgkmcnt(0)" ::: "memory"); \
        __builtin_amdgcn_sched_barrier(0);                 \
    } while (0)

// 0-3: W2/b2 fold; 4-99: WTJ repack [jg][c][6]; 100-107: conv_w transpose;
// 108: A_log structure check; 109-620: m_out_w transpose.
__global__ void k_prep(const float* __restrict__ W_embed, const float* __restrict__ b_embed,
                       const float* __restrict__ m_in_w, const float* __restrict__ xproj_w,
                       const float* __restrict__ conv_w, const float* __restrict__ A_log,
                       const float* __restrict__ dec_A_log, const float* __restrict__ m_out_w,
                       float* __restrict__ ws, int* __restrict__ flags) {
    int bid = blockIdx.x, tid = threadIdx.x;
    if (bid < 4) {
        int j = bid * 256 + tid;
        float acc[8] = {0, 0, 0, 0, 0, 0, 0, 0};
        float accb = 0.f;
        for (int c = 0; c < DMODEL; ++c) {
            float w = m_in_w[c * 1024 + j];
            accb += b_embed[c] * w;
#pragma unroll
            for (int i = 0; i < 8; ++i) acc[i] += W_embed[i * DMODEL + c] * w;
        }
#pragma unroll
        for (int i = 0; i < 8; ++i) ws[W2_OFF + i * 1024 + j] = acc[i];
        ws[B2_OFF + j] = accb;
    } else if (bid < 100) {
        int o = (bid - 4) * 256 + tid;  // < 24576
        int jg = o / 3072, r = o % 3072, c = r / 6, jj = r % 6;
        ws[WTJ_OFF + o] = xproj_w[c * 48 + jg * 6 + jj];
    } else if (bid < 108) {
        int idx = (bid - 100) * 256 + tid;  // < 2048
        int tap = idx / 512, c = idx % 512;
        ws[CWT_OFF + tap * 512 + c] = conv_w[c * 4 + tap];
    } else if (bid == 108) {
        __shared__ int oks[2];
        if (tid == 0) { oks[0] = 1; oks[1] = 1; }
        __syncthreads();
        int bad_e = 0, bad_d = 0;
        for (int i = tid; i < DI * NST; i += 256) {
            int dd = i / NST, n = i % NST;
            float a0 = __expf(A_log[dd * NST]);
            float an = __expf(A_log[dd * NST + n]);
            if (fabsf(an - (n + 1) * a0) > 1e-4f * (n + 1)) bad_e = 1;
        }
        for (int i = tid; i < NLAYERS * DID * NST; i += 256) {
            int dd = i / NST, n = i % NST;
            float a0 = __expf(dec_A_log[dd * NST]);
            float an = __expf(dec_A_log[dd * NST + n]);
            if (fabsf(an - (n + 1) * a0) > 1e-4f * (n + 1)) bad_d = 1;
        }
        if (bad_e) atomicAnd(&oks[0], 0);
        if (bad_d) atomicAnd(&oks[1], 0);
        __syncthreads();
        if (tid == 0) { flags[0] = oks[0]; flags[1] = oks[1]; }
    } else {
        int idx = (bid - 109) * 256 + tid;  // < 131072
        int c = idx >> 8, j = idx & 255;
        ws[MOWT_OFF + j * 512 + c] = m_out_w[idx];
    }
}

// conv + proj: block = (b, t-half of 50). c-TILED (4 tiles of 128 channels),
// double-buffered 32KB LDS tiles -> 64KB total -> 2 blocks/CU (4 waves/SIMD).
// Phase 1 (tile): thread=(c_l, tq) computes xs+conv+silu for its 11-13 rows
// (3-row xs halo recompute), stores transposed with pair swizzle
// xcT[bf][c_l*64 + (t ^ ((c_l>>1)&31))] (write & read both <=2-way, free).
// Phase 2 (tile): wave = j-group (6 cols), lane = t; weights via VMEM
// double-buffered VGPR prefetch (wave-uniform float4 loads, vmcnt pipe).
// Schedule: phase1(ct+1, buf^1) issued BEFORE phase2(ct, buf) in the same
// barrier interval -> global-load latency hides under FMA streams.
__global__ void __launch_bounds__(512, 2) k_convproj(
    const float* __restrict__ x, const float* __restrict__ ws, const float* __restrict__ conv_b,
    const float* __restrict__ W2g, float* __restrict__ proj_g, float* __restrict__ silu_z) {
    __shared__ __align__(16) float xcT[2][128 * 64];
    __shared__ __align__(16) float x_l[53 * 8];
    const float* cwT = ws + CWT_OFF;
    const int b = blockIdx.x >> 1, half = blockIdx.x & 1;
    const int t0 = half * 50;
    const int tid = threadIdx.x, lane = tid & 63, wv = tid >> 6;
    const float* x_b = x + (size_t)b * SEQ * 8;

    // stage x rows t0-3..t0+49
    if (tid < 424) {
        int r = tid >> 3, k = tid & 7;
        int t = t0 + r - 3;
        x_l[tid] = (t >= 0) ? x_b[t * 8 + k] : 0.f;
    }
    __syncthreads();

    if (half == 1) {  // silu_z from t=99 (row 52), W2 cols 512..1023
        float z = ws[B2_OFF + 512 + tid];
#pragma unroll
        for (int i = 0; i < 8; ++i) z += x_l[52 * 8 + i] * W2g[i * 1024 + 512 + tid];
        silu_z[b * DI + tid] = silu_f(z);
    }

    const int c_l = tid & 127, tq = tid >> 7;  // tq is wave-uniform (2 waves/tq)
    const int swz1 = (c_l >> 1) & 31;
    const int s0 = 3 + tq * 13;                // first conv-out row s
    const int s1 = (tq == 3) ? 52 : s0 + 12;   // last conv-out row s

    auto phase1 = [&](int ct, int bf) {
        const int c = ct * 128 + c_l;
        float w2c[8];
#pragma unroll
        for (int i = 0; i < 8; ++i) w2c[i] = W2g[i * 1024 + c];
        const float biasc = ws[B2_OFF + c];
        const float cw0 = cwT[c], cw1 = cwT[512 + c], cw2 = cwT[1024 + c], cw3 = cwT[1536 + c];
        const float cb = conv_b[c];
        float win0, win1, win2;
        {
            float w[3];
#pragma unroll
            for (int k = 0; k < 3; ++k) {
                int s = s0 - 3 + k;
                float v = 0.f;
                if (half | (s >= 3)) {  // t = t0+s-3 >= 0
                    float4 xa = *(const float4*)&x_l[s * 8];
                    float4 xb4 = *(const float4*)&x_l[s * 8 + 4];
                    v = biasc;
                    v = fmaf(xa.x, w2c[0], v); v = fmaf(xa.y, w2c[1], v);
                    v = fmaf(xa.z, w2c[2], v); v = fmaf(xa.w, w2c[3], v);
                    v = fmaf(xb4.x, w2c[4], v); v = fmaf(xb4.y, w2c[5], v);
                    v = fmaf(xb4.z, w2c[6], v); v = fmaf(xb4.w, w2c[7], v);
                }
                w[k] = v;
            }
            win0 = w[0]; win1 = w[1]; win2 = w[2];
        }
        for (int s = s0; s <= s1; ++s) {  // wave-uniform trip count
            float4 xa = *(const float4*)&x_l[s * 8];
            float4 xb4 = *(const float4*)&x_l[s * 8 + 4];
            float xs = biasc;
            xs = fmaf(xa.x, w2c[0], xs); xs = fmaf(xa.y, w2c[1], xs);
            xs = fmaf(xa.z, w2c[2], xs); xs = fmaf(xa.w, w2c[3], xs);
            xs = fmaf(xb4.x, w2c[4], xs); xs = fmaf(xb4.y, w2c[5], xs);
            xs = fmaf(xb4.z, w2c[6], xs); xs = fmaf(xb4.w, w2c[7], xs);
            float cvv = cb + win0 * cw0 + win1 * cw1 + win2 * cw2 + xs * cw3;
            xcT[bf][(c_l << 6) + ((s - 3) ^ swz1)] = silu_f(cvv);
            win0 = win1; win1 = win2; win2 = xs;
        }
    };

    const int l = (lane < 50) ? lane : 49;
    float a0 = 0.f, a1 = 0.f, a2 = 0.f, a3 = 0.f, a4 = 0.f, a5 = 0.f;

#define WE(W, e)                                                      \
    ((((e) & 3) == 0)   ? (W)[(e) >> 2].x                             \
     : (((e) & 3) == 1) ? (W)[(e) >> 2].y                             \
     : (((e) & 3) == 2) ? (W)[(e) >> 2].z                             \
                        : (W)[(e) >> 2].w)

#define LOADW(W, wjg, g)                                              \
    do {                                                              \
        const float4* _p = (const float4*)((wjg) + (g) * 48);         \
        _Pragma("unroll") for (int _m = 0; _m < 12; ++_m) (W)[_m] = _p[_m]; \
    } while (0)

#define COMP(W, bf, g)                                                \
    do {                                                              \
        float _xq[8];                                                 \
        _Pragma("unroll") for (int _p = 0; _p < 4; ++_p) {            \
            const int _c0 = (g) * 8 + _p * 2;                         \
            const int _s = (_c0 >> 1) & 31;                           \
            const float* _pp = &xcT[bf][(_c0 << 6) + (l ^ _s)];       \
            _xq[2 * _p] = _pp[0];                                     \
            _xq[2 * _p + 1] = _pp[64];                                \
        }                                                             \
        _Pragma("unroll") for (int _i = 0; _i < 8; ++_i) {            \
            a0 = fmaf(_xq[_i], WE(W, _i * 6 + 0), a0);                \
            a1 = fmaf(_xq[_i], WE(W, _i * 6 + 1), a1);                \
            a2 = fmaf(_xq[_i], WE(W, _i * 6 + 2), a2);                \
            a3 = fmaf(_xq[_i], WE(W, _i * 6 + 3), a3);                \
            a4 = fmaf(_xq[_i], WE(W, _i * 6 + 4), a4);                \
            a5 = fmaf(_xq[_i], WE(W, _i * 6 + 5), a5);                \
        }                                                             \
    } while (0)

    auto phase2 = [&](int ct, int bf) {
        const float* wjg = ws + WTJ_OFF + wv * 3072 + ct * 768;  // [jg][c][6] tile
        float4 WA[12], WB[12];
        LOADW(WA, wjg, 0);
        for (int g = 0; g < 16; g += 2) {
            LOADW(WB, wjg, g + 1);
            COMP(WA, bf, g);
            LOADW(WA, wjg, (g + 2 < 16) ? (g + 2) : 15);
            COMP(WB, bf, g + 1);
        }
    };

    phase1(0, 0);
    __syncthreads();
    for (int ct = 0; ct < 4; ++ct) {
        if (ct < 3) phase1(ct + 1, (ct + 1) & 1);  // fill other buffer
        phase2(ct, ct & 1);
        __syncthreads();
    }
#undef COMP
#undef LOADW
#undef WE

    if (lane < 50) {
        float* dst = proj_g + ((size_t)b * SEQ + t0 + lane) * 48 + wv * 6;
        *(float2*)(dst + 0) = make_float2(a0, a1);
        *(float2*)(dst + 2) = make_float2(a2, a3);
        *(float2*)(dst + 4) = make_float2(a4, a5);
    }
}

// SSM scan: SGPR-prefetched rows, log-tree powers (unchanged).
#define SCAN_STEP(SA, SB, SX)                                                        \
    do {                                                                             \
        float xsv = biasc;                                                           \
        xsv = fmaf((SX)[0], w2c[0], xsv); xsv = fmaf((SX)[1], w2c[1], xsv);          \
        xsv = fmaf((SX)[2], w2c[2], xsv); xsv = fmaf((SX)[3], w2c[3], xsv);          \
        xsv = fmaf((SX)[4], w2c[4], xsv); xsv = fmaf((SX)[5], w2c[5], xsv);          \
        xsv = fmaf((SX)[6], w2c[6], xsv); xsv = fmaf((SX)[7], w2c[7], xsv);          \
        float cv = cb + win0 * cw0 + win1 * cw1 + win2 * cw2 + xsv * cw3;            \
        win0 = win1; win1 = win2; win2 = xsv;                                        \
        xcv = silu_f(cv);                                                            \
        float acc = bdt;                                                             \
        acc = fmaf((SA)[0], wr[0], acc);  acc = fmaf((SA)[1], wr[1], acc);           \
        acc = fmaf((SA)[2], wr[2], acc);  acc = fmaf((SA)[3], wr[3], acc);           \
        acc = fmaf((SA)[4], wr[4], acc);  acc = fmaf((SA)[5], wr[5], acc);           \
        acc = fmaf((SA)[6], wr[6], acc);  acc = fmaf((SA)[7], wr[7], acc);           \
        acc = fmaf((SA)[8], wr[8], acc);  acc = fmaf((SA)[9], wr[9], acc);           \
        acc = fmaf((SA)[10], wr[10], acc); acc = fmaf((SA)[11], wr[11], acc);        \
        acc = fmaf((SA)[12], wr[12], acc); acc = fmaf((SA)[13], wr[13], acc);        \
        acc = fmaf((SA)[14], wr[14], acc); acc = fmaf((SA)[15], wr[15], acc);        \
        float dtv = (acc > 20.f) ? acc : __logf(1.f + __expf(acc));                  \
        S += dtv;                                                                    \
        float sv = dtv * xcv;                                                        \
        if (fast) {                                                                  \
            float E1 = __expf(dtv * An0);                                            \
            float E2 = E1 * E1, E3 = E2 * E1, E4 = E2 * E2;                          \
            float E5 = E4 * E1, E6 = E4 * E2, E7 = E4 * E3, E8 = E4 * E4;            \
            float E9 = E8 * E1, E10 = E8 * E2, E11 = E8 * E3, E12 = E8 * E4;         \
            float E13 = E8 * E5, E14 = E8 * E6, E15 = E8 * E7, E16 = E8 * E8;        \
            h[0] = fmaf(h[0], E1, sv * (SB)[0]);   h[1] = fmaf(h[1], E2, sv * (SB)[1]); \
            h[2] = fmaf(h[2], E3, sv * (SB)[2]);   h[3] = fmaf(h[3], E4, sv * (SB)[3]); \
            h[4] = fmaf(h[4], E5, sv * (SB)[4]);   h[5] = fmaf(h[5], E6, sv * (SB)[5]); \
            h[6] = fmaf(h[6], E7, sv * (SB)[6]);   h[7] = fmaf(h[7], E8, sv * (SB)[7]); \
            h[8] = fmaf(h[8], E9, sv * (SB)[8]);   h[9] = fmaf(h[9], E10, sv * (SB)[9]); \
            h[10] = fmaf(h[10], E11, sv * (SB)[10]); h[11] = fmaf(h[11], E12, sv * (SB)[11]); \
            h[12] = fmaf(h[12], E13, sv * (SB)[12]); h[13] = fmaf(h[13], E14, sv * (SB)[13]); \
            h[14] = fmaf(h[14], E15, sv * (SB)[14]); h[15] = fmaf(h[15], E16, sv * (SB)[15]); \
        } else {                                                                     \
            _Pragma("unroll")                                                        \
            for (int n = 0; n < NST; ++n) {                                          \
                float Ann = -__expf(A_log[d * NST + n]);                             \
                h[n] = fmaf(h[n], __expf(dtv * Ann), sv * (SB)[n]);                  \
            }                                                                        \
        }                                                                            \
    } while (0)

__global__ void __launch_bounds__(512, 4) k_scan(
    const float* __restrict__ x, const float* __restrict__ ws, const float* __restrict__ conv_b,
    const float* __restrict__ proj_g, const float* __restrict__ A_log,
    const float* __restrict__ dtw, const float* __restrict__ dtb,
    const float* __restrict__ Dvec, const float* __restrict__ silu_z,
    const int* __restrict__ flags, float* __restrict__ y_g) {
    __shared__ float h1_s[256 * 17];
    const int b = blockIdx.x >> 1, dgrp = blockIdx.x & 1;
    const int tid = threadIdx.x, half = tid >> 8, dl = tid & 255;
    const int d = dgrp * 256 + dl;
    const float* W2 = ws + W2_OFF;
    const float* b2 = ws + B2_OFF;
    const float* cwT = ws + CWT_OFF;
    const float* proj_b = proj_g + (size_t)b * SEQ * 48;
    const float* x_b = x + (size_t)b * SEQ * 8;

    float w2c[8];
#pragma unroll
    for (int i = 0; i < 8; ++i) w2c[i] = W2[i * 1024 + d];
    float biasc = b2[d];
    float cw0 = cwT[d], cw1 = cwT[512 + d], cw2 = cwT[1024 + d], cw3 = cwT[1536 + d];
    float cb = conv_b[d];
    float wr[DTRANK];
#pragma unroll
    for (int r = 0; r < DTRANK; ++r) wr[r] = dtw[r * DI + d];
    float bdt = dtb[d];
    float An0 = -__expf(A_log[d * NST]);
    const bool fast = flags[0] != 0;
    float h[NST];
#pragma unroll
    for (int n = 0; n < NST; ++n) h[n] = 0.f;
    float S = 0.f, xcv = 0.f;
    const int tstart = half * 50;

    float win0 = 0.f, win1 = 0.f, win2 = 0.f;
    for (int tt = tstart - 3; tt < tstart; ++tt) {
        float v = 0.f;
        if (tt >= 0) {
            const float4* xr = (const float4*)(x_b + tt * 8);
            float4 xa = xr[0], xb4 = xr[1];
            v = biasc + xa.x * w2c[0] + xa.y * w2c[1] + xa.z * w2c[2] + xa.w * w2c[3] +
                xb4.x * w2c[4] + xb4.y * w2c[5] + xb4.z * w2c[6] + xb4.w * w2c[7];
        }
        win0 = win1; win1 = win2; win2 = v;
    }

    int poff = rfl(tstart * 192);
    int xoff = rfl(tstart * 32);
    sf16 a0, a1, b0, b1;
    sf8 ax, bx;
    SL2(a0, a1, proj_b, poff, poff + 64);
    SLX(ax, x_b, xoff);
    SL_WAIT();
    for (int it = 0; it < 25; ++it) {
        int p1 = poff + 192, x1 = xoff + 32;
        SL2(b0, b1, proj_b, p1, p1 + 64);
        SLX(bx, x_b, x1);
        SCAN_STEP(a0, a1, ax);
        SL_WAIT();
        int p2 = (it < 24) ? poff + 384 : p1;
        int x2 = (it < 24) ? xoff + 64 : x1;
        SL2(a0, a1, proj_b, p2, p2 + 64);
        SLX(ax, x_b, x2);
        SCAN_STEP(b0, b1, bx);
        SL_WAIT();
        poff += 384;
        xoff += 64;
    }

    if (half == 0) {
#pragma unroll
        for (int n = 0; n < NST; ++n) h1_s[dl * 17 + n] = h[n];
    }
    __syncthreads();
    if (half == 1) {
        sf16 cC;
        SLC(cC, proj_b, (SEQ - 1) * 192 + 128);
        SL_WAIT();
        float yv = Dvec[d] * xcv;
        if (fast) {
            float G1 = __expf(S * An0);
            float G2 = G1 * G1, G3 = G2 * G1, G4 = G2 * G2;
            float G5 = G4 * G1, G6 = G4 * G2, G7 = G4 * G3, G8 = G4 * G4;
            float G9 = G8 * G1, G10 = G8 * G2, G11 = G8 * G3, G12 = G8 * G4;
            float G13 = G8 * G5, G14 = G8 * G6, G15 = G8 * G7, G16 = G8 * G8;
            float Gs[NST] = {G1, G2, G3, G4, G5, G6, G7, G8,
                             G9, G10, G11, G12, G13, G14, G15, G16};
#pragma unroll
            for (int n = 0; n < NST; ++n) {
                float hf = fmaf(h1_s[dl * 17 + n], Gs[n], h[n]);
                yv = fmaf(hf, cC[n], yv);
            }
        } else {
#pragma unroll
            for (int n = 0; n < NST; ++n) {
                float Ann = -__expf(A_log[d * NST + n]);
                float hf = fmaf(h1_s[dl * 17 + n], __expf(S * Ann), h[n]);
                yv = fmaf(hf, cC[n], yv);
            }
        }
        y_g[(size_t)b * DI + d] = yv * silu_z[(size_t)b * DI + d];
    }
}

// flow matvec (transposed weights, b128 row reads) + 3-layer decoder.
__global__ void __launch_bounds__(512, 2) k_flowdec(
    const float* __restrict__ x, const float* __restrict__ y_g,
    const float* __restrict__ mowt, const float* __restrict__ dec_in_w,
    const float* __restrict__ dec_in_b, const float* __restrict__ dec_flow_w,
    const float* __restrict__ dec_dt_w, const float* __restrict__ dec_dt_b,
    const float* __restrict__ dec_A_log, const float* __restrict__ dec_D,
    const float* __restrict__ dec_out_w, const float* __restrict__ dec_out_b,
    const int* __restrict__ flags, float* __restrict__ out) {
    __shared__ __align__(16) float y_s[DI];
    __shared__ __align__(16) float pf_s[48];
    __shared__ float red_s[DMODEL];
    __shared__ float flow_s[DMODEL];
    __shared__ float bbox_s[4];
    __shared__ float dred_s[8][4];
    const int b = blockIdx.x, tid = threadIdx.x, d = tid;
    const int lane = tid & 63, wv = tid >> 6;
    const bool dfast = flags[1] != 0;
    y_s[d] = y_g[(size_t)b * DI + d];
    if (tid < 4) bbox_s[tid] = x[(size_t)(b * SEQ + SEQ - 1) * 8 + tid];
    __syncthreads();
    {
        int j = tid >> 1, p = tid & 1;
        const float* wrow = mowt + (size_t)j * 512 + p * 256;
        const float* yrow = &y_s[p * 256];
        float fa = 0.f;
#pragma unroll 4
        for (int i = 0; i < 64; ++i) {
            float4 wq = *(const float4*)&wrow[4 * i];
            float4 yq = *(const float4*)&yrow[4 * i];
            fa += wq.x * yq.x + wq.y * yq.y + wq.z * yq.z + wq.w * yq.w;
        }
        if (p == 1) red_s[j] = fa;
        __syncthreads();
        if (p == 0) flow_s[j] = fa + red_s[j];
    }
    float h[NST];
#pragma unroll
    for (int n = 0; n < NST; ++n) h[n] = 0.f;
    __syncthreads();
    for (int L = 0; L < NLAYERS; ++L) {
        float epre = dec_in_b[L * 1024 + d];
        float rpre = dec_in_b[L * 1024 + 512 + d];
#pragma unroll
        for (int i = 0; i < 4; ++i) {
            float bx = bbox_s[i];
            epre += bx * dec_in_w[(L * 4 + i) * 1024 + d];
            rpre += bx * dec_in_w[(L * 4 + i) * 1024 + 512 + d];
        }
        float e = silu_f(epre);
        float fl4[4];
#pragma unroll
        for (int k = 0; k < 4; ++k) fl4[k] = flow_s[lane + 64 * k];
        float pj[6];
#pragma unroll
        for (int jj = 0; jj < 6; ++jj) {
            float a = 0.f;
#pragma unroll
            for (int k = 0; k < 4; ++k)
                a += fl4[k] * dec_flow_w[L * DMODEL * 48 + (lane + 64 * k) * 48 + wv * 6 + jj];
            pj[jj] = wave64_sum(a);
        }
        if (lane == 63) {
#pragma unroll
            for (int jj = 0; jj < 6; ++jj) pf_s[wv * 6 + jj] = pj[jj];
        }
        __syncthreads();
        float4 p0 = *(const float4*)&pf_s[0];
        float4 p1 = *(const float4*)&pf_s[4];
        float4 p2 = *(const float4*)&pf_s[8];
        float4 p3 = *(const float4*)&pf_s[12];
        float dtd = dec_dt_b[L * DID + d];
        dtd += p0.x * dec_dt_w[(L * 16 + 0) * DID + d] + p0.y * dec_dt_w[(L * 16 + 1) * DID + d] +
               p0.z * dec_dt_w[(L * 16 + 2) * DID + d] + p0.w * dec_dt_w[(L * 16 + 3) * DID + d];
        dtd += p1.x * dec_dt_w[(L * 16 + 4) * DID + d] + p1.y * dec_dt_w[(L * 16 + 5) * DID + d] +
               p1.z * dec_dt_w[(L * 16 + 6) * DID + d] + p1.w * dec_dt_w[(L * 16 + 7) * DID + d];
        dtd += p2.x * dec_dt_w[(L * 16 + 8) * DID + d] + p2.y * dec_dt_w[(L * 16 + 9) * DID + d] +
               p2.z * dec_dt_w[(L * 16 + 10) * DID + d] + p2.w * dec_dt_w[(L * 16 + 11) * DID + d];
        dtd += p3.x * dec_dt_w[(L * 16 + 12) * DID + d] + p3.y * dec_dt_w[(L * 16 + 13) * DID + d] +
               p3.z * dec_dt_w[(L * 16 + 14) * DID + d] + p3.w * dec_dt_w[(L * 16 + 15) * DID + d];
        dtd = (dtd > 20.f) ? dtd : __logf(1.f + __expf(dtd));
        float4 B0 = *(const float4*)&pf_s[16];
        float4 B1 = *(const float4*)&pf_s[20];
        float4 B2 = *(const float4*)&pf_s[24];
        float4 B3 = *(const float4*)&pf_s[28];
        float4 C0 = *(const float4*)&pf_s[32];
        float4 C1 = *(const float4*)&pf_s[36];
        float4 C2 = *(const float4*)&pf_s[40];
        float4 C3 = *(const float4*)&pf_s[44];
        float Bv[NST] = {B0.x, B0.y, B0.z, B0.w, B1.x, B1.y, B1.z, B1.w,
                         B2.x, B2.y, B2.z, B2.w, B3.x, B3.y, B3.z, B3.w};
        float Cv[NST] = {C0.x, C0.y, C0.z, C0.w, C1.x, C1.y, C1.z, C1.w,
                         C2.x, C2.y, C2.z, C2.w, C3.x, C3.y, C3.z, C3.w};
        float yd = 0.f;
        if (dfast) {
            float Ad0 = -__expf(dec_A_log[(L * DID + d) * NST]);
            float E1 = __expf(dtd * Ad0);
            float E2 = E1 * E1, E3 = E2 * E1, E4 = E2 * E2;
            float E5 = E4 * E1, E6 = E4 * E2, E7 = E4 * E3, E8 = E4 * E4;
            float E9 = E8 * E1, E10 = E8 * E2, E11 = E8 * E3, E12 = E8 * E4;
            float E13 = E8 * E5, E14 = E8 * E6, E15 = E8 * E7, E16 = E8 * E8;
            float Es[NST] = {E1, E2, E3, E4, E5, E6, E7, E8,
                             E9, E10, E11, E12, E13, E14, E15, E16};
#pragma unroll
            for (int n = 0; n < NST; ++n) {
                h[n] = fmaf(h[n], Es[n], e * (dtd * Bv[n]));
                yd += h[n] * Cv[n];
            }
        } else {
#pragma unroll
            for (int n = 0; n < NST; ++n) {
                float Adn = -__expf(dec_A_log[(L * DID + d) * NST + n]);
                h[n] = fmaf(h[n], __expf(dtd * Adn), e * (dtd * Bv[n]));
                yd += h[n] * Cv[n];
            }
        }
        yd += dec_D[L * DID + d] * e;
        yd *= silu_f(rpre);
#pragma unroll
        for (int jo = 0; jo < 4; ++jo) {
            float v = wave64_sum(yd * dec_out_w[(L * DID + d) * 4 + jo]);
            if (lane == 63) dred_s[wv][jo] = v;
        }
        __syncthreads();
        if (tid < 4) {
            float a2 = dec_out_b[L * 4 + tid];
#pragma unroll
            for (int w = 0; w < 8; ++w) a2 += dred_s[w][tid];
            bbox_s[tid] = a2;
            if (L == NLAYERS - 1) out[b * 4 + tid] = a2;
        }
        __syncthreads();
    }
}

extern "C" void kernel_launch(void* const* d_in, const int* in_sizes, int n_in,
                              void* d_out, int out_size, void* d_ws, size_t ws_size,
                              hipStream_t stream) {
    const float* x          = (const float*)d_in[0];
    const float* W_embed    = (const float*)d_in[1];
    const float* b_embed    = (const float*)d_in[2];
    const float* m_in_w     = (const float*)d_in[3];
    const float* m_conv_w   = (const float*)d_in[4];
    const float* m_conv_b   = (const float*)d_in[5];
    const float* m_xproj_w  = (const float*)d_in[6];
    const float* m_dtproj_w = (const float*)d_in[7];
    const float* m_dtproj_b = (const float*)d_in[8];
    const float* m_A_log    = (const float*)d_in[9];
    const float* m_D        = (const float*)d_in[10];
    const float* m_out_w    = (const float*)d_in[11];
    const float* dec_in_w   = (const float*)d_in[12];
    const float* dec_in_b   = (const float*)d_in[13];
    const float* dec_flow_w = (const float*)d_in[14];
    const float* dec_dt_w   = (const float*)d_in[15];
    const float* dec_dt_b   = (const float*)d_in[16];
    const float* dec_A_log  = (const float*)d_in[17];
    const float* dec_D      = (const float*)d_in[18];
    const float* dec_out_w  = (const float*)d_in[19];
    const float* dec_out_b  = (const float*)d_in[20];

    float* ws = (float*)d_ws;
    int* flags = (int*)(ws + FLAG_OFF);
    float* proj_g = ws + PROJ_OFF;
    float* siluz = ws + SILUZ_OFF;
    float* y_g = ws + Y_OFF;
    float* mowt = ws + MOWT_OFF;

    k_prep<<<621, 256, 0, stream>>>(W_embed, b_embed, m_in_w, m_xproj_w, m_conv_w,
                                    m_A_log, dec_A_log, m_out_w, ws, flags);
    k_convproj<<<BATCH * 2, 512, 0, stream>>>(x, ws, m_conv_b, ws + W2_OFF, proj_g, siluz);
    k_scan<<<BATCH * 2, 512, 0, stream>>>(x, ws, m_conv_b, proj_g, m_A_log, m_dtproj_w,
                                          m_dtproj_b, m_D, siluz, flags, y_g);
    k_flowdec<<<BATCH, 512, 0, stream>>>(x, y_g, mowt, dec_in_w, dec_in_b, dec_flow_w,
                                         dec_dt_w, dec_dt_b, dec_A_log, dec_D, dec_out_w,
                                         dec_out_b, flags, (float*)d_out);
}

// Round 12
// 151.975 us; speedup vs baseline: 1.3245x; 1.3245x over previous
//
#include <hip/hip_runtime.h>
#include <math.h>

#define BATCH 256
#define SEQ 100
#define DMODEL 256
#define DI 512
#define DID 512
#define NST 16
#define DTRANK 16
#define DCONV 4
#define NLAYERS 3

// workspace layout (floats)
#define W2_OFF 0              // 8*1024
#define B2_OFF 8192           // 1024
#define WTJ_OFF 9216          // 8*512*6 j-grouped tight xproj: [jg][c][6]
#define CWT_OFF 33792         // 4*512 transposed conv_w
#define FLAG_OFF 35840        // 2 ints
#define PROJ_OFF 35848        // 25600*48
#define SILUZ_OFF 1264648     // 256*512
#define Y_OFF 1395720         // 256*512
#define MOWT_OFF 1526792      // 256*512 m_out_w transposed [j][c]

__device__ __forceinline__ float silu_f(float x) { return x / (1.0f + __expf(-x)); }

#define DPP_ADD(v, ctrl, rmask) \
    v += __int_as_float(__builtin_amdgcn_update_dpp(0, __float_as_int(v), ctrl, rmask, 0xF, false))

__device__ __forceinline__ float wave64_sum(float v) {
    DPP_ADD(v, 0xB1, 0xF);
    DPP_ADD(v, 0x4E, 0xF);
    DPP_ADD(v, 0x141, 0xF);
    DPP_ADD(v, 0x140, 0xF);
    DPP_ADD(v, 0x142, 0xA);
    DPP_ADD(v, 0x143, 0xC);
    return v;
}

typedef float sf16 __attribute__((ext_vector_type(16)));
typedef float sf8 __attribute__((ext_vector_type(8)));

__device__ __forceinline__ int rfl(int v) { return __builtin_amdgcn_readfirstlane(v); }

#define SL2(dA, dB, base, offA, offB)                    \
    asm volatile("s_load_dwordx16 %0, %2, %3\n\t"        \
                 "s_load_dwordx16 %1, %2, %4"            \
                 : "=&s"(dA), "=&s"(dB)                  \
                 : "s"(base), "s"(offA), "s"(offB))
#define SLX(dX, base, off) \
    asm volatile("s_load_dwordx8 %0, %1, %2" : "=&s"(dX) : "s"(base), "s"(off))
#define SLC(dC, base, off) \
    asm volatile("s_load_dwordx16 %0, %1, %2" : "=&s"(dC) : "s"(base), "s"(off))
// 24 floats (4 c's worth of 6 weights): dwordx16 + dwordx8 at +64B
#define SLW(d16, d8, base, off)                          \
    asm volatile("s_load_dwordx16 %0, %2, %3\n\t"        \
                 "s_load_dwordx8 %1, %2, %4"             \
                 : "=&s"(d16), "=&s"(d8)                 \
                 : "s"(base), "s"(off), "s"((off) + 64))
#define SL_WAIT()                                          \
    do {                                                   \
        asm volatile("s_waitcnt lgkmcnt(0)" ::: "memory"); \
        __builtin_amdgcn_sched_barrier(0);                 \
    } while (0)

// 0-3: W2/b2 fold; 4-99: WTJ repack [jg][c][6]; 100-107: conv_w transpose;
// 108: A_log structure check; 109-620: m_out_w transpose.
__global__ void k_prep(const float* __restrict__ W_embed, const float* __restrict__ b_embed,
                       const float* __restrict__ m_in_w, const float* __restrict__ xproj_w,
                       const float* __restrict__ conv_w, const float* __restrict__ A_log,
                       const float* __restrict__ dec_A_log, const float* __restrict__ m_out_w,
                       float* __restrict__ ws, int* __restrict__ flags) {
    int bid = blockIdx.x, tid = threadIdx.x;
    if (bid < 4) {
        int j = bid * 256 + tid;
        float acc[8] = {0, 0, 0, 0, 0, 0, 0, 0};
        float accb = 0.f;
        for (int c = 0; c < DMODEL; ++c) {
            float w = m_in_w[c * 1024 + j];
            accb += b_embed[c] * w;
#pragma unroll
            for (int i = 0; i < 8; ++i) acc[i] += W_embed[i * DMODEL + c] * w;
        }
#pragma unroll
        for (int i = 0; i < 8; ++i) ws[W2_OFF + i * 1024 + j] = acc[i];
        ws[B2_OFF + j] = accb;
    } else if (bid < 100) {
        int o = (bid - 4) * 256 + tid;  // < 24576
        int jg = o / 3072, r = o % 3072, c = r / 6, jj = r % 6;
        ws[WTJ_OFF + o] = xproj_w[c * 48 + jg * 6 + jj];
    } else if (bid < 108) {
        int idx = (bid - 100) * 256 + tid;  // < 2048
        int tap = idx / 512, c = idx % 512;
        ws[CWT_OFF + tap * 512 + c] = conv_w[c * 4 + tap];
    } else if (bid == 108) {
        __shared__ int oks[2];
        if (tid == 0) { oks[0] = 1; oks[1] = 1; }
        __syncthreads();
        int bad_e = 0, bad_d = 0;
        for (int i = tid; i < DI * NST; i += 256) {
            int dd = i / NST, n = i % NST;
            float a0 = __expf(A_log[dd * NST]);
            float an = __expf(A_log[dd * NST + n]);
            if (fabsf(an - (n + 1) * a0) > 1e-4f * (n + 1)) bad_e = 1;
        }
        for (int i = tid; i < NLAYERS * DID * NST; i += 256) {
            int dd = i / NST, n = i % NST;
            float a0 = __expf(dec_A_log[dd * NST]);
            float an = __expf(dec_A_log[dd * NST + n]);
            if (fabsf(an - (n + 1) * a0) > 1e-4f * (n + 1)) bad_d = 1;
        }
        if (bad_e) atomicAnd(&oks[0], 0);
        if (bad_d) atomicAnd(&oks[1], 0);
        __syncthreads();
        if (tid == 0) { flags[0] = oks[0]; flags[1] = oks[1]; }
    } else {
        int idx = (bid - 109) * 256 + tid;  // < 131072
        int c = idx >> 8, j = idx & 255;
        ws[MOWT_OFF + j * 512 + c] = m_out_w[idx];
    }
}

// conv + proj: block = (b, t-half of 50). c-TILED by 64 (8 tiles), xcT double
// buffer = 32KB LDS -> high occupancy. Phase 1 (tile): thread=(c_l, tq)
// computes xs+conv+silu, stores pair-swizzled xcT[bf][c_l*64 + (t^((c_l>>1)&31))].
// Phase 2 (tile): wave = j-group, lane = t; FIRST copies its 64 xv values
// LDS->REGISTERS (one lgkmcnt(0)), THEN runs a pure SMEM+FMA loop: s_load
// dwordx16+x8 ping-pong (scan-proven pattern) with 24 FMA cover per wait.
// No LDS ops inside the weight loop -> no lgkm mixing.
__global__ void __launch_bounds__(512, 4) k_convproj(
    const float* __restrict__ x, const float* __restrict__ ws, const float* __restrict__ conv_b,
    const float* __restrict__ W2g, float* __restrict__ proj_g, float* __restrict__ silu_z) {
    __shared__ __align__(16) float xcT[2][64 * 64];
    __shared__ __align__(16) float x_l[53 * 8];
    const float* cwT = ws + CWT_OFF;
    const float* wtj = ws + WTJ_OFF;  // block-uniform base for s_load
    const int b = blockIdx.x >> 1, half = blockIdx.x & 1;
    const int t0 = half * 50;
    const int tid = threadIdx.x, lane = tid & 63, wv = tid >> 6;
    const float* x_b = x + (size_t)b * SEQ * 8;

    // stage x rows t0-3..t0+49
    if (tid < 424) {
        int r = tid >> 3, k = tid & 7;
        int t = t0 + r - 3;
        x_l[tid] = (t >= 0) ? x_b[t * 8 + k] : 0.f;
    }
    __syncthreads();

    if (half == 1) {  // silu_z from t=99 (row 52), W2 cols 512..1023
        float z = ws[B2_OFF + 512 + tid];
#pragma unroll
        for (int i = 0; i < 8; ++i) z += x_l[52 * 8 + i] * W2g[i * 1024 + 512 + tid];
        silu_z[b * DI + tid] = silu_f(z);
    }

    const int c_l = tid & 63, tq = tid >> 6;   // tq wave-uniform (1 wave per tq)
    const int swz1 = (c_l >> 1) & 31;
    const int s0 = 3 + tq * 7;                 // first conv-out row s
    const int s1 = (s0 + 6 < 52) ? s0 + 6 : 52;  // rows: tq0-6: 7, tq7: 1

    auto phase1 = [&](int ct, int bf) {
        const int c = ct * 64 + c_l;
        float w2c[8];
#pragma unroll
        for (int i = 0; i < 8; ++i) w2c[i] = W2g[i * 1024 + c];
        const float biasc = ws[B2_OFF + c];
        const float cw0 = cwT[c], cw1 = cwT[512 + c], cw2 = cwT[1024 + c], cw3 = cwT[1536 + c];
        const float cb = conv_b[c];
        float win0, win1, win2;
        {
            float w[3];
#pragma unroll
            for (int k = 0; k < 3; ++k) {
                int s = s0 - 3 + k;
                float v = 0.f;
                if (half | (s >= 3)) {  // t = t0+s-3 >= 0
                    float4 xa = *(const float4*)&x_l[s * 8];
                    float4 xb4 = *(const float4*)&x_l[s * 8 + 4];
                    v = biasc;
                    v = fmaf(xa.x, w2c[0], v); v = fmaf(xa.y, w2c[1], v);
                    v = fmaf(xa.z, w2c[2], v); v = fmaf(xa.w, w2c[3], v);
                    v = fmaf(xb4.x, w2c[4], v); v = fmaf(xb4.y, w2c[5], v);
                    v = fmaf(xb4.z, w2c[6], v); v = fmaf(xb4.w, w2c[7], v);
                }
                w[k] = v;
            }
            win0 = w[0]; win1 = w[1]; win2 = w[2];
        }
        for (int s = s0; s <= s1; ++s) {  // wave-uniform trip count
            float4 xa = *(const float4*)&x_l[s * 8];
            float4 xb4 = *(const float4*)&x_l[s * 8 + 4];
            float xs = biasc;
            xs = fmaf(xa.x, w2c[0], xs); xs = fmaf(xa.y, w2c[1], xs);
            xs = fmaf(xa.z, w2c[2], xs); xs = fmaf(xa.w, w2c[3], xs);
            xs = fmaf(xb4.x, w2c[4], xs); xs = fmaf(xb4.y, w2c[5], xs);
            xs = fmaf(xb4.z, w2c[6], xs); xs = fmaf(xb4.w, w2c[7], xs);
            float cvv = cb + win0 * cw0 + win1 * cw1 + win2 * cw2 + xs * cw3;
            xcT[bf][(c_l << 6) + ((s - 3) ^ swz1)] = silu_f(cvv);
            win0 = win1; win1 = win2; win2 = xs;
        }
    };

    const int l = (lane < 50) ? lane : 49;
    float a0 = 0.f, a1 = 0.f, a2 = 0.f, a3 = 0.f, a4 = 0.f, a5 = 0.f;

#define COMP4(W16, W8, g)                                              \
    do {                                                               \
        float _x0 = xv[4 * (g)], _x1 = xv[4 * (g) + 1];                \
        float _x2 = xv[4 * (g) + 2], _x3 = xv[4 * (g) + 3];            \
        a0 = fmaf(_x0, (W16)[0], a0);  a1 = fmaf(_x0, (W16)[1], a1);   \
        a2 = fmaf(_x0, (W16)[2], a2);  a3 = fmaf(_x0, (W16)[3], a3);   \
        a4 = fmaf(_x0, (W16)[4], a4);  a5 = fmaf(_x0, (W16)[5], a5);   \
        a0 = fmaf(_x1, (W16)[6], a0);  a1 = fmaf(_x1, (W16)[7], a1);   \
        a2 = fmaf(_x1, (W16)[8], a2);  a3 = fmaf(_x1, (W16)[9], a3);   \
        a4 = fmaf(_x1, (W16)[10], a4); a5 = fmaf(_x1, (W16)[11], a5);  \
        a0 = fmaf(_x2, (W16)[12], a0); a1 = fmaf(_x2, (W16)[13], a1);  \
        a2 = fmaf(_x2, (W16)[14], a2); a3 = fmaf(_x2, (W16)[15], a3);  \
        a4 = fmaf(_x2, (W8)[0], a4);   a5 = fmaf(_x2, (W8)[1], a5);    \
        a0 = fmaf(_x3, (W8)[2], a0);   a1 = fmaf(_x3, (W8)[3], a1);    \
        a2 = fmaf(_x3, (W8)[4], a2);   a3 = fmaf(_x3, (W8)[5], a3);    \
        a4 = fmaf(_x3, (W8)[6], a4);   a5 = fmaf(_x3, (W8)[7], a5);    \
    } while (0)

    auto phase2 = [&](int ct, int bf) {
        // (1) xv tile: LDS -> registers (paired reads share swizzle)
        float xv[64];
#pragma unroll
        for (int p = 0; p < 32; ++p) {
            const float* pp = &xcT[bf][(p << 7) + (l ^ (p & 31))];
            xv[2 * p] = pp[0];
            xv[2 * p + 1] = pp[64];
        }
        // (2) pure SMEM+FMA weight loop (scan-style 2-deep ping-pong)
        int off = rfl(wv * 12288 + ct * 1536);  // bytes into WTJ
        sf16 A16, B16;
        sf8 A8, B8;
        SLW(A16, A8, wtj, off);
        SL_WAIT();  // also drains the xv ds_reads
        for (int g = 0; g < 16; g += 2) {
            SLW(B16, B8, wtj, off + 96);
            COMP4(A16, A8, g);
            SL_WAIT();
            int o2 = (g + 2 < 16) ? off + 192 : off + 96;  // clamp final prefetch
            SLW(A16, A8, wtj, o2);
            COMP4(B16, B8, g + 1);
            SL_WAIT();
            off += 192;
        }
    };

    phase1(0, 0);
    __syncthreads();
    for (int ct = 0; ct < 8; ++ct) {
        if (ct < 7) phase1(ct + 1, (ct + 1) & 1);  // fill other buffer
        phase2(ct, ct & 1);
        __syncthreads();
    }
#undef COMP4

    if (lane < 50) {
        float* dst = proj_g + ((size_t)b * SEQ + t0 + lane) * 48 + wv * 6;
        *(float2*)(dst + 0) = make_float2(a0, a1);
        *(float2*)(dst + 2) = make_float2(a2, a3);
        *(float2*)(dst + 4) = make_float2(a4, a5);
    }
}

// SSM scan: SGPR-prefetched rows, log-tree powers (unchanged).
#define SCAN_STEP(SA, SB, SX)                                                        \
    do {                                                                             \
        float xsv = biasc;                                                           \
        xsv = fmaf((SX)[0], w2c[0], xsv); xsv = fmaf((SX)[1], w2c[1], xsv);          \
        xsv = fmaf((SX)[2], w2c[2], xsv); xsv = fmaf((SX)[3], w2c[3], xsv);          \
        xsv = fmaf((SX)[4], w2c[4], xsv); xsv = fmaf((SX)[5], w2c[5], xsv);          \
        xsv = fmaf((SX)[6], w2c[6], xsv); xsv = fmaf((SX)[7], w2c[7], xsv);          \
        float cv = cb + win0 * cw0 + win1 * cw1 + win2 * cw2 + xsv * cw3;            \
        win0 = win1; win1 = win2; win2 = xsv;                                        \
        xcv = silu_f(cv);                                                            \
        float acc = bdt;                                                             \
        acc = fmaf((SA)[0], wr[0], acc);  acc = fmaf((SA)[1], wr[1], acc);           \
        acc = fmaf((SA)[2], wr[2], acc);  acc = fmaf((SA)[3], wr[3], acc);           \
        acc = fmaf((SA)[4], wr[4], acc);  acc = fmaf((SA)[5], wr[5], acc);           \
        acc = fmaf((SA)[6], wr[6], acc);  acc = fmaf((SA)[7], wr[7], acc);           \
        acc = fmaf((SA)[8], wr[8], acc);  acc = fmaf((SA)[9], wr[9], acc);           \
        acc = fmaf((SA)[10], wr[10], acc); acc = fmaf((SA)[11], wr[11], acc);        \
        acc = fmaf((SA)[12], wr[12], acc); acc = fmaf((SA)[13], wr[13], acc);        \
        acc = fmaf((SA)[14], wr[14], acc); acc = fmaf((SA)[15], wr[15], acc);        \
        float dtv = (acc > 20.f) ? acc : __logf(1.f + __expf(acc));                  \
        S += dtv;                                                                    \
        float sv = dtv * xcv;                                                        \
        if (fast) {                                                                  \
            float E1 = __expf(dtv * An0);                                            \
            float E2 = E1 * E1, E3 = E2 * E1, E4 = E2 * E2;                          \
            float E5 = E4 * E1, E6 = E4 * E2, E7 = E4 * E3, E8 = E4 * E4;            \
            float E9 = E8 * E1, E10 = E8 * E2, E11 = E8 * E3, E12 = E8 * E4;         \
            float E13 = E8 * E5, E14 = E8 * E6, E15 = E8 * E7, E16 = E8 * E8;        \
            h[0] = fmaf(h[0], E1, sv * (SB)[0]);   h[1] = fmaf(h[1], E2, sv * (SB)[1]); \
            h[2] = fmaf(h[2], E3, sv * (SB)[2]);   h[3] = fmaf(h[3], E4, sv * (SB)[3]); \
            h[4] = fmaf(h[4], E5, sv * (SB)[4]);   h[5] = fmaf(h[5], E6, sv * (SB)[5]); \
            h[6] = fmaf(h[6], E7, sv * (SB)[6]);   h[7] = fmaf(h[7], E8, sv * (SB)[7]); \
            h[8] = fmaf(h[8], E9, sv * (SB)[8]);   h[9] = fmaf(h[9], E10, sv * (SB)[9]); \
            h[10] = fmaf(h[10], E11, sv * (SB)[10]); h[11] = fmaf(h[11], E12, sv * (SB)[11]); \
            h[12] = fmaf(h[12], E13, sv * (SB)[12]); h[13] = fmaf(h[13], E14, sv * (SB)[13]); \
            h[14] = fmaf(h[14], E15, sv * (SB)[14]); h[15] = fmaf(h[15], E16, sv * (SB)[15]); \
        } else {                                                                     \
            _Pragma("unroll")                                                        \
            for (int n = 0; n < NST; ++n) {                                          \
                float Ann = -__expf(A_log[d * NST + n]);                             \
                h[n] = fmaf(h[n], __expf(dtv * Ann), sv * (SB)[n]);                  \
            }                                                                        \
        }                                                                            \
    } while (0)

__global__ void __launch_bounds__(512, 4) k_scan(
    const float* __restrict__ x, const float* __restrict__ ws, const float* __restrict__ conv_b,
    const float* __restrict__ proj_g, const float* __restrict__ A_log,
    const float* __restrict__ dtw, const float* __restrict__ dtb,
    const float* __restrict__ Dvec, const float* __restrict__ silu_z,
    const int* __restrict__ flags, float* __restrict__ y_g) {
    __shared__ float h1_s[256 * 17];
    const int b = blockIdx.x >> 1, dgrp = blockIdx.x & 1;
    const int tid = threadIdx.x, half = tid >> 8, dl = tid & 255;
    const int d = dgrp * 256 + dl;
    const float* W2 = ws + W2_OFF;
    const float* b2 = ws + B2_OFF;
    const float* cwT = ws + CWT_OFF;
    const float* proj_b = proj_g + (size_t)b * SEQ * 48;
    const float* x_b = x + (size_t)b * SEQ * 8;

    float w2c[8];
#pragma unroll
    for (int i = 0; i < 8; ++i) w2c[i] = W2[i * 1024 + d];
    float biasc = b2[d];
    float cw0 = cwT[d], cw1 = cwT[512 + d], cw2 = cwT[1024 + d], cw3 = cwT[1536 + d];
    float cb = conv_b[d];
    float wr[DTRANK];
#pragma unroll
    for (int r = 0; r < DTRANK; ++r) wr[r] = dtw[r * DI + d];
    float bdt = dtb[d];
    float An0 = -__expf(A_log[d * NST]);
    const bool fast = flags[0] != 0;
    float h[NST];
#pragma unroll
    for (int n = 0; n < NST; ++n) h[n] = 0.f;
    float S = 0.f, xcv = 0.f;
    const int tstart = half * 50;

    float win0 = 0.f, win1 = 0.f, win2 = 0.f;
    for (int tt = tstart - 3; tt < tstart; ++tt) {
        float v = 0.f;
        if (tt >= 0) {
            const float4* xr = (const float4*)(x_b + tt * 8);
            float4 xa = xr[0], xb4 = xr[1];
            v = biasc + xa.x * w2c[0] + xa.y * w2c[1] + xa.z * w2c[2] + xa.w * w2c[3] +
                xb4.x * w2c[4] + xb4.y * w2c[5] + xb4.z * w2c[6] + xb4.w * w2c[7];
        }
        win0 = win1; win1 = win2; win2 = v;
    }

    int poff = rfl(tstart * 192);
    int xoff = rfl(tstart * 32);
    sf16 a0, a1, b0, b1;
    sf8 ax, bx;
    SL2(a0, a1, proj_b, poff, poff + 64);
    SLX(ax, x_b, xoff);
    SL_WAIT();
    for (int it = 0; it < 25; ++it) {
        int p1 = poff + 192, x1 = xoff + 32;
        SL2(b0, b1, proj_b, p1, p1 + 64);
        SLX(bx, x_b, x1);
        SCAN_STEP(a0, a1, ax);
        SL_WAIT();
        int p2 = (it < 24) ? poff + 384 : p1;
        int x2 = (it < 24) ? xoff + 64 : x1;
        SL2(a0, a1, proj_b, p2, p2 + 64);
        SLX(ax, x_b, x2);
        SCAN_STEP(b0, b1, bx);
        SL_WAIT();
        poff += 384;
        xoff += 64;
    }

    if (half == 0) {
#pragma unroll
        for (int n = 0; n < NST; ++n) h1_s[dl * 17 + n] = h[n];
    }
    __syncthreads();
    if (half == 1) {
        sf16 cC;
        SLC(cC, proj_b, (SEQ - 1) * 192 + 128);
        SL_WAIT();
        float yv = Dvec[d] * xcv;
        if (fast) {
            float G1 = __expf(S * An0);
            float G2 = G1 * G1, G3 = G2 * G1, G4 = G2 * G2;
            float G5 = G4 * G1, G6 = G4 * G2, G7 = G4 * G3, G8 = G4 * G4;
            float G9 = G8 * G1, G10 = G8 * G2, G11 = G8 * G3, G12 = G8 * G4;
            float G13 = G8 * G5, G14 = G8 * G6, G15 = G8 * G7, G16 = G8 * G8;
            float Gs[NST] = {G1, G2, G3, G4, G5, G6, G7, G8,
                             G9, G10, G11, G12, G13, G14, G15, G16};
#pragma unroll
            for (int n = 0; n < NST; ++n) {
                float hf = fmaf(h1_s[dl * 17 + n], Gs[n], h[n]);
                yv = fmaf(hf, cC[n], yv);
            }
        } else {
#pragma unroll
            for (int n = 0; n < NST; ++n) {
                float Ann = -__expf(A_log[d * NST + n]);
                float hf = fmaf(h1_s[dl * 17 + n], __expf(S * Ann), h[n]);
                yv = fmaf(hf, cC[n], yv);
            }
        }
        y_g[(size_t)b * DI + d] = yv * silu_z[(size_t)b * DI + d];
    }
}

// flow matvec (transposed weights, b128 row reads) + 3-layer decoder.
__global__ void __launch_bounds__(512, 2) k_flowdec(
    const float* __restrict__ x, const float* __restrict__ y_g,
    const float* __restrict__ mowt, const float* __restrict__ dec_in_w,
    const float* __restrict__ dec_in_b, const float* __restrict__ dec_flow_w,
    const float* __restrict__ dec_dt_w, const float* __restrict__ dec_dt_b,
    const float* __restrict__ dec_A_log, const float* __restrict__ dec_D,
    const float* __restrict__ dec_out_w, const float* __restrict__ dec_out_b,
    const int* __restrict__ flags, float* __restrict__ out) {
    __shared__ __align__(16) float y_s[DI];
    __shared__ __align__(16) float pf_s[48];
    __shared__ float red_s[DMODEL];
    __shared__ float flow_s[DMODEL];
    __shared__ float bbox_s[4];
    __shared__ float dred_s[8][4];
    const int b = blockIdx.x, tid = threadIdx.x, d = tid;
    const int lane = tid & 63, wv = tid >> 6;
    const bool dfast = flags[1] != 0;
    y_s[d] = y_g[(size_t)b * DI + d];
    if (tid < 4) bbox_s[tid] = x[(size_t)(b * SEQ + SEQ - 1) * 8 + tid];
    __syncthreads();
    {
        int j = tid >> 1, p = tid & 1;
        const float* wrow = mowt + (size_t)j * 512 + p * 256;
        const float* yrow = &y_s[p * 256];
        float fa = 0.f;
#pragma unroll 4
        for (int i = 0; i < 64; ++i) {
            float4 wq = *(const float4*)&wrow[4 * i];
            float4 yq = *(const float4*)&yrow[4 * i];
            fa += wq.x * yq.x + wq.y * yq.y + wq.z * yq.z + wq.w * yq.w;
        }
        if (p == 1) red_s[j] = fa;
        __syncthreads();
        if (p == 0) flow_s[j] = fa + red_s[j];
    }
    float h[NST];
#pragma unroll
    for (int n = 0; n < NST; ++n) h[n] = 0.f;
    __syncthreads();
    for (int L = 0; L < NLAYERS; ++L) {
        float epre = dec_in_b[L * 1024 + d];
        float rpre = dec_in_b[L * 1024 + 512 + d];
#pragma unroll
        for (int i = 0; i < 4; ++i) {
            float bx = bbox_s[i];
            epre += bx * dec_in_w[(L * 4 + i) * 1024 + d];
            rpre += bx * dec_in_w[(L * 4 + i) * 1024 + 512 + d];
        }
        float e = silu_f(epre);
        float fl4[4];
#pragma unroll
        for (int k = 0; k < 4; ++k) fl4[k] = flow_s[lane + 64 * k];
        float pj[6];
#pragma unroll
        for (int jj = 0; jj < 6; ++jj) {
            float a = 0.f;
#pragma unroll
            for (int k = 0; k < 4; ++k)
                a += fl4[k] * dec_flow_w[L * DMODEL * 48 + (lane + 64 * k) * 48 + wv * 6 + jj];
            pj[jj] = wave64_sum(a);
        }
        if (lane == 63) {
#pragma unroll
            for (int jj = 0; jj < 6; ++jj) pf_s[wv * 6 + jj] = pj[jj];
        }
        __syncthreads();
        float4 p0 = *(const float4*)&pf_s[0];
        float4 p1 = *(const float4*)&pf_s[4];
        float4 p2 = *(const float4*)&pf_s[8];
        float4 p3 = *(const float4*)&pf_s[12];
        float dtd = dec_dt_b[L * DID + d];
        dtd += p0.x * dec_dt_w[(L * 16 + 0) * DID + d] + p0.y * dec_dt_w[(L * 16 + 1) * DID + d] +
               p0.z * dec_dt_w[(L * 16 + 2) * DID + d] + p0.w * dec_dt_w[(L * 16 + 3) * DID + d];
        dtd += p1.x * dec_dt_w[(L * 16 + 4) * DID + d] + p1.y * dec_dt_w[(L * 16 + 5) * DID + d] +
               p1.z * dec_dt_w[(L * 16 + 6) * DID + d] + p1.w * dec_dt_w[(L * 16 + 7) * DID + d];
        dtd += p2.x * dec_dt_w[(L * 16 + 8) * DID + d] + p2.y * dec_dt_w[(L * 16 + 9) * DID + d] +
               p2.z * dec_dt_w[(L * 16 + 10) * DID + d] + p2.w * dec_dt_w[(L * 16 + 11) * DID + d];
        dtd += p3.x * dec_dt_w[(L * 16 + 12) * DID + d] + p3.y * dec_dt_w[(L * 16 + 13) * DID + d] +
               p3.z * dec_dt_w[(L * 16 + 14) * DID + d] + p3.w * dec_dt_w[(L * 16 + 15) * DID + d];
        dtd = (dtd > 20.f) ? dtd : __logf(1.f + __expf(dtd));
        float4 B0 = *(const float4*)&pf_s[16];
        float4 B1 = *(const float4*)&pf_s[20];
        float4 B2 = *(const float4*)&pf_s[24];
        float4 B3 = *(const float4*)&pf_s[28];
        float4 C0 = *(const float4*)&pf_s[32];
        float4 C1 = *(const float4*)&pf_s[36];
        float4 C2 = *(const float4*)&pf_s[40];
        float4 C3 = *(const float4*)&pf_s[44];
        float Bv[NST] = {B0.x, B0.y, B0.z, B0.w, B1.x, B1.y, B1.z, B1.w,
                         B2.x, B2.y, B2.z, B2.w, B3.x, B3.y, B3.z, B3.w};
        float Cv[NST] = {C0.x, C0.y, C0.z, C0.w, C1.x, C1.y, C1.z, C1.w,
                         C2.x, C2.y, C2.z, C2.w, C3.x, C3.y, C3.z, C3.w};
        float yd = 0.f;
        if (dfast) {
            float Ad0 = -__expf(dec_A_log[(L * DID + d) * NST]);
            float E1 = __expf(dtd * Ad0);
            float E2 = E1 * E1, E3 = E2 * E1, E4 = E2 * E2;
            float E5 = E4 * E1, E6 = E4 * E2, E7 = E4 * E3, E8 = E4 * E4;
            float E9 = E8 * E1, E10 = E8 * E2, E11 = E8 * E3, E12 = E8 * E4;
            float E13 = E8 * E5, E14 = E8 * E6, E15 = E8 * E7, E16 = E8 * E8;
            float Es[NST] = {E1, E2, E3, E4, E5, E6, E7, E8,
                             E9, E10, E11, E12, E13, E14, E15, E16};
#pragma unroll
            for (int n = 0; n < NST; ++n) {
                h[n] = fmaf(h[n], Es[n], e * (dtd * Bv[n]));
                yd += h[n] * Cv[n];
            }
        } else {
#pragma unroll
            for (int n = 0; n < NST; ++n) {
                float Adn = -__expf(dec_A_log[(L * DID + d) * NST + n]);
                h[n] = fmaf(h[n], __expf(dtd * Adn), e * (dtd * Bv[n]));
                yd += h[n] * Cv[n];
            }
        }
        yd += dec_D[L * DID + d] * e;
        yd *= silu_f(rpre);
#pragma unroll
        for (int jo = 0; jo < 4; ++jo) {
            float v = wave64_sum(yd * dec_out_w[(L * DID + d) * 4 + jo]);
            if (lane == 63) dred_s[wv][jo] = v;
        }
        __syncthreads();
        if (tid < 4) {
            float a2 = dec_out_b[L * 4 + tid];
#pragma unroll
            for (int w = 0; w < 8; ++w) a2 += dred_s[w][tid];
            bbox_s[tid] = a2;
            if (L == NLAYERS - 1) out[b * 4 + tid] = a2;
        }
        __syncthreads();
    }
}

extern "C" void kernel_launch(void* const* d_in, const int* in_sizes, int n_in,
                              void* d_out, int out_size, void* d_ws, size_t ws_size,
                              hipStream_t stream) {
    const float* x          = (const float*)d_in[0];
    const float* W_embed    = (const float*)d_in[1];
    const float* b_embed    = (const float*)d_in[2];
    const float* m_in_w     = (const float*)d_in[3];
    const float* m_conv_w   = (const float*)d_in[4];
    const float* m_conv_b   = (const float*)d_in[5];
    const float* m_xproj_w  = (const float*)d_in[6];
    const float* m_dtproj_w = (const float*)d_in[7];
    const float* m_dtproj_b = (const float*)d_in[8];
    const float* m_A_log    = (const float*)d_in[9];
    const float* m_D        = (const float*)d_in[10];
    const float* m_out_w    = (const float*)d_in[11];
    const float* dec_in_w   = (const float*)d_in[12];
    const float* dec_in_b   = (const float*)d_in[13];
    const float* dec_flow_w = (const float*)d_in[14];
    const float* dec_dt_w   = (const float*)d_in[15];
    const float* dec_dt_b   = (const float*)d_in[16];
    const float* dec_A_log  = (const float*)d_in[17];
    const float* dec_D      = (const float*)d_in[18];
    const float* dec_out_w  = (const float*)d_in[19];
    const float* dec_out_b  = (const float*)d_in[20];

    float* ws = (float*)d_ws;
    int* flags = (int*)(ws + FLAG_OFF);
    float* proj_g = ws + PROJ_OFF;
    float* siluz = ws + SILUZ_OFF;
    float* y_g = ws + Y_OFF;
    float* mowt = ws + MOWT_OFF;

    k_prep<<<621, 256, 0, stream>>>(W_embed, b_embed, m_in_w, m_xproj_w, m_conv_w,
                                    m_A_log, dec_A_log, m_out_w, ws, flags);
    k_convproj<<<BATCH * 2, 512, 0, stream>>>(x, ws, m_conv_b, ws + W2_OFF, proj_g, siluz);
    k_scan<<<BATCH * 2, 512, 0, stream>>>(x, ws, m_conv_b, proj_g, m_A_log, m_dtproj_w,
                                          m_dtproj_b, m_D, siluz, flags, y_g);
    k_flowdec<<<BATCH, 512, 0, stream>>>(x, y_g, mowt, dec_in_w, dec_in_b, dec_flow_w,
                                         dec_dt_w, dec_dt_b, dec_A_log, dec_D, dec_out_w,
                                         dec_out_b, flags, (float*)d_out);
}

// Round 13
// 151.729 us; speedup vs baseline: 1.3266x; 1.0016x over previous
//
#include <hip/hip_runtime.h>
#include <math.h>

#define BATCH 256
#define SEQ 100
#define DMODEL 256
#define DI 512
#define DID 512
#define NST 16
#define DTRANK 16
#define DCONV 4
#define NLAYERS 3

// workspace layout (floats)
#define W2_OFF 0              // 8*1024
#define B2_OFF 8192           // 1024
#define WTJ_OFF 9216          // 8*512*6 j-grouped tight xproj: [jg][c][6]
#define CWT_OFF 33792         // 4*512 transposed conv_w
#define FLAG_OFF 35840        // 2 ints
#define PROJ_OFF 35848        // 25600*48
#define SILUZ_OFF 1264648     // 256*512
#define Y_OFF 1395720         // 256*512
#define MOWT_OFF 1526792      // 256*512 m_out_w transposed [j][c]

__device__ __forceinline__ float silu_f(float x) { return x / (1.0f + __expf(-x)); }

#define DPP_ADD(v, ctrl, rmask) \
    v += __int_as_float(__builtin_amdgcn_update_dpp(0, __float_as_int(v), ctrl, rmask, 0xF, false))

__device__ __forceinline__ float wave64_sum(float v) {
    DPP_ADD(v, 0xB1, 0xF);
    DPP_ADD(v, 0x4E, 0xF);
    DPP_ADD(v, 0x141, 0xF);
    DPP_ADD(v, 0x140, 0xF);
    DPP_ADD(v, 0x142, 0xA);
    DPP_ADD(v, 0x143, 0xC);
    return v;
}

typedef float sf16 __attribute__((ext_vector_type(16)));
typedef float sf8 __attribute__((ext_vector_type(8)));

__device__ __forceinline__ int rfl(int v) { return __builtin_amdgcn_readfirstlane(v); }

#define SL2(dA, dB, base, offA, offB)                    \
    asm volatile("s_load_dwordx16 %0, %2, %3\n\t"        \
                 "s_load_dwordx16 %1, %2, %4"            \
                 : "=&s"(dA), "=&s"(dB)                  \
                 : "s"(base), "s"(offA), "s"(offB))
#define SLX(dX, base, off) \
    asm volatile("s_load_dwordx8 %0, %1, %2" : "=&s"(dX) : "s"(base), "s"(off))
#define SLC(dC, base, off) \
    asm volatile("s_load_dwordx16 %0, %1, %2" : "=&s"(dC) : "s"(base), "s"(off))
// 24 floats (4 c's worth of 6 weights): dwordx16 + dwordx8 at +64B
#define SLW(d16, d8, base, off)                          \
    asm volatile("s_load_dwordx16 %0, %2, %3\n\t"        \
                 "s_load_dwordx8 %1, %2, %4"             \
                 : "=&s"(d16), "=&s"(d8)                 \
                 : "s"(base), "s"(off), "s"((off) + 64))
#define SL_WAIT()                                          \
    do {                                                   \
        asm volatile("s_waitcnt lgkmcnt(0)" ::: "memory"); \
        __builtin_amdgcn_sched_barrier(0);                 \
    } while (0)

// 0-3: W2/b2 fold; 4-99: WTJ repack [jg][c][6]; 100-107: conv_w transpose;
// 108: A_log structure check; 109-620: m_out_w transpose.
__global__ void k_prep(const float* __restrict__ W_embed, const float* __restrict__ b_embed,
                       const float* __restrict__ m_in_w, const float* __restrict__ xproj_w,
                       const float* __restrict__ conv_w, const float* __restrict__ A_log,
                       const float* __restrict__ dec_A_log, const float* __restrict__ m_out_w,
                       float* __restrict__ ws, int* __restrict__ flags) {
    int bid = blockIdx.x, tid = threadIdx.x;
    if (bid < 4) {
        int j = bid * 256 + tid;
        float acc[8] = {0, 0, 0, 0, 0, 0, 0, 0};
        float accb = 0.f;
        for (int c = 0; c < DMODEL; ++c) {
            float w = m_in_w[c * 1024 + j];
            accb += b_embed[c] * w;
#pragma unroll
            for (int i = 0; i < 8; ++i) acc[i] += W_embed[i * DMODEL + c] * w;
        }
#pragma unroll
        for (int i = 0; i < 8; ++i) ws[W2_OFF + i * 1024 + j] = acc[i];
        ws[B2_OFF + j] = accb;
    } else if (bid < 100) {
        int o = (bid - 4) * 256 + tid;  // < 24576
        int jg = o / 3072, r = o % 3072, c = r / 6, jj = r % 6;
        ws[WTJ_OFF + o] = xproj_w[c * 48 + jg * 6 + jj];
    } else if (bid < 108) {
        int idx = (bid - 100) * 256 + tid;  // < 2048
        int tap = idx / 512, c = idx % 512;
        ws[CWT_OFF + tap * 512 + c] = conv_w[c * 4 + tap];
    } else if (bid == 108) {
        __shared__ int oks[2];
        if (tid == 0) { oks[0] = 1; oks[1] = 1; }
        __syncthreads();
        int bad_e = 0, bad_d = 0;
        for (int i = tid; i < DI * NST; i += 256) {
            int dd = i / NST, n = i % NST;
            float a0 = __expf(A_log[dd * NST]);
            float an = __expf(A_log[dd * NST + n]);
            if (fabsf(an - (n + 1) * a0) > 1e-4f * (n + 1)) bad_e = 1;
        }
        for (int i = tid; i < NLAYERS * DID * NST; i += 256) {
            int dd = i / NST, n = i % NST;
            float a0 = __expf(dec_A_log[dd * NST]);
            float an = __expf(dec_A_log[dd * NST + n]);
            if (fabsf(an - (n + 1) * a0) > 1e-4f * (n + 1)) bad_d = 1;
        }
        if (bad_e) atomicAnd(&oks[0], 0);
        if (bad_d) atomicAnd(&oks[1], 0);
        __syncthreads();
        if (tid == 0) { flags[0] = oks[0]; flags[1] = oks[1]; }
    } else {
        int idx = (bid - 109) * 256 + tid;  // < 131072
        int c = idx >> 8, j = idx & 255;
        ws[MOWT_OFF + j * 512 + c] = m_out_w[idx];
    }
}

// conv + proj: block = (b, t-half of 50). c-TILED by 64 (8 tiles), xcT double
// buffer = 32KB LDS -> high occupancy. Phase 1 (tile): thread=(c_l, tq)
// computes xs+conv+silu, stores pair-swizzled xcT[bf][c_l*64 + (t^((c_l>>1)&31))].
// Phase 2 (tile): wave = j-group, lane = t; copies its 64 xv values
// LDS->REGISTERS, then a FULLY-UNROLLED pure SMEM+FMA loop (s_load dwordx16+x8
// ping-pong). Full unroll keeps xv[] register-resident (rule #20: runtime
// index -> scratch was round 12's 2x cost, VGPR_Count=60 proved it).
__global__ void __launch_bounds__(512, 4) k_convproj(
    const float* __restrict__ x, const float* __restrict__ ws, const float* __restrict__ conv_b,
    const float* __restrict__ W2g, float* __restrict__ proj_g, float* __restrict__ silu_z) {
    __shared__ __align__(16) float xcT[2][64 * 64];
    __shared__ __align__(16) float x_l[53 * 8];
    const float* cwT = ws + CWT_OFF;
    const float* wtj = ws + WTJ_OFF;  // block-uniform base for s_load
    const int b = blockIdx.x >> 1, half = blockIdx.x & 1;
    const int t0 = half * 50;
    const int tid = threadIdx.x, lane = tid & 63, wv = tid >> 6;
    const float* x_b = x + (size_t)b * SEQ * 8;

    // stage x rows t0-3..t0+49
    if (tid < 424) {
        int r = tid >> 3, k = tid & 7;
        int t = t0 + r - 3;
        x_l[tid] = (t >= 0) ? x_b[t * 8 + k] : 0.f;
    }
    __syncthreads();

    if (half == 1) {  // silu_z from t=99 (row 52), W2 cols 512..1023
        float z = ws[B2_OFF + 512 + tid];
#pragma unroll
        for (int i = 0; i < 8; ++i) z += x_l[52 * 8 + i] * W2g[i * 1024 + 512 + tid];
        silu_z[b * DI + tid] = silu_f(z);
    }

    const int c_l = tid & 63, tq = tid >> 6;   // tq wave-uniform (1 wave per tq)
    const int swz1 = (c_l >> 1) & 31;
    const int s0 = 3 + tq * 7;                 // first conv-out row s
    const int s1 = (s0 + 6 < 52) ? s0 + 6 : 52;  // rows: tq0-6: 7, tq7: 1

    auto phase1 = [&](int ct, int bf) {
        const int c = ct * 64 + c_l;
        float w2c[8];
#pragma unroll
        for (int i = 0; i < 8; ++i) w2c[i] = W2g[i * 1024 + c];
        const float biasc = ws[B2_OFF + c];
        const float cw0 = cwT[c], cw1 = cwT[512 + c], cw2 = cwT[1024 + c], cw3 = cwT[1536 + c];
        const float cb = conv_b[c];
        float win0, win1, win2;
        {
            float w[3];
#pragma unroll
            for (int k = 0; k < 3; ++k) {
                int s = s0 - 3 + k;
                float v = 0.f;
                if (half | (s >= 3)) {  // t = t0+s-3 >= 0
                    float4 xa = *(const float4*)&x_l[s * 8];
                    float4 xb4 = *(const float4*)&x_l[s * 8 + 4];
                    v = biasc;
                    v = fmaf(xa.x, w2c[0], v); v = fmaf(xa.y, w2c[1], v);
                    v = fmaf(xa.z, w2c[2], v); v = fmaf(xa.w, w2c[3], v);
                    v = fmaf(xb4.x, w2c[4], v); v = fmaf(xb4.y, w2c[5], v);
                    v = fmaf(xb4.z, w2c[6], v); v = fmaf(xb4.w, w2c[7], v);
                }
                w[k] = v;
            }
            win0 = w[0]; win1 = w[1]; win2 = w[2];
        }
        for (int s = s0; s <= s1; ++s) {  // wave-uniform trip count
            float4 xa = *(const float4*)&x_l[s * 8];
            float4 xb4 = *(const float4*)&x_l[s * 8 + 4];
            float xs = biasc;
            xs = fmaf(xa.x, w2c[0], xs); xs = fmaf(xa.y, w2c[1], xs);
            xs = fmaf(xa.z, w2c[2], xs); xs = fmaf(xa.w, w2c[3], xs);
            xs = fmaf(xb4.x, w2c[4], xs); xs = fmaf(xb4.y, w2c[5], xs);
            xs = fmaf(xb4.z, w2c[6], xs); xs = fmaf(xb4.w, w2c[7], xs);
            float cvv = cb + win0 * cw0 + win1 * cw1 + win2 * cw2 + xs * cw3;
            xcT[bf][(c_l << 6) + ((s - 3) ^ swz1)] = silu_f(cvv);
            win0 = win1; win1 = win2; win2 = xs;
        }
    };

    const int l = (lane < 50) ? lane : 49;
    float a0 = 0.f, a1 = 0.f, a2 = 0.f, a3 = 0.f, a4 = 0.f, a5 = 0.f;

#define COMP4(W16, W8, g)                                              \
    do {                                                               \
        float _x0 = xv[4 * (g)], _x1 = xv[4 * (g) + 1];                \
        float _x2 = xv[4 * (g) + 2], _x3 = xv[4 * (g) + 3];            \
        a0 = fmaf(_x0, (W16)[0], a0);  a1 = fmaf(_x0, (W16)[1], a1);   \
        a2 = fmaf(_x0, (W16)[2], a2);  a3 = fmaf(_x0, (W16)[3], a3);   \
        a4 = fmaf(_x0, (W16)[4], a4);  a5 = fmaf(_x0, (W16)[5], a5);   \
        a0 = fmaf(_x1, (W16)[6], a0);  a1 = fmaf(_x1, (W16)[7], a1);   \
        a2 = fmaf(_x1, (W16)[8], a2);  a3 = fmaf(_x1, (W16)[9], a3);   \
        a4 = fmaf(_x1, (W16)[10], a4); a5 = fmaf(_x1, (W16)[11], a5);  \
        a0 = fmaf(_x2, (W16)[12], a0); a1 = fmaf(_x2, (W16)[13], a1);  \
        a2 = fmaf(_x2, (W16)[14], a2); a3 = fmaf(_x2, (W16)[15], a3);  \
        a4 = fmaf(_x2, (W8)[0], a4);   a5 = fmaf(_x2, (W8)[1], a5);    \
        a0 = fmaf(_x3, (W8)[2], a0);   a1 = fmaf(_x3, (W8)[3], a1);    \
        a2 = fmaf(_x3, (W8)[4], a2);   a3 = fmaf(_x3, (W8)[5], a3);    \
        a4 = fmaf(_x3, (W8)[6], a4);   a5 = fmaf(_x3, (W8)[7], a5);    \
    } while (0)

    auto phase2 = [&](int ct, int bf) {
        // (1) xv tile: LDS -> registers (paired reads share swizzle)
        float xv[64];
#pragma unroll
        for (int p = 0; p < 32; ++p) {
            const float* pp = &xcT[bf][(p << 7) + (l ^ (p & 31))];
            xv[2 * p] = pp[0];
            xv[2 * p + 1] = pp[64];
        }
        // (2) pure SMEM+FMA weight loop, FULLY UNROLLED (static xv indices)
        int off = rfl(wv * 12288 + ct * 1536);  // bytes into WTJ
        sf16 A16, B16;
        sf8 A8, B8;
        SLW(A16, A8, wtj, off);
        SL_WAIT();  // also drains the xv ds_reads
#pragma unroll
        for (int g = 0; g < 16; g += 2) {
            SLW(B16, B8, wtj, off + 96);
            COMP4(A16, A8, g);
            SL_WAIT();
            int o2 = (g + 2 < 16) ? off + 192 : off + 96;  // clamp final prefetch
            SLW(A16, A8, wtj, o2);
            COMP4(B16, B8, g + 1);
            SL_WAIT();
            off += 192;
        }
    };

    phase1(0, 0);
    __syncthreads();
    for (int ct = 0; ct < 8; ++ct) {
        if (ct < 7) phase1(ct + 1, (ct + 1) & 1);  // fill other buffer
        phase2(ct, ct & 1);
        __syncthreads();
    }
#undef COMP4

    if (lane < 50) {
        float* dst = proj_g + ((size_t)b * SEQ + t0 + lane) * 48 + wv * 6;
        *(float2*)(dst + 0) = make_float2(a0, a1);
        *(float2*)(dst + 2) = make_float2(a2, a3);
        *(float2*)(dst + 4) = make_float2(a4, a5);
    }
}

// SSM scan: SGPR-prefetched rows, log-tree powers (unchanged).
#define SCAN_STEP(SA, SB, SX)                                                        \
    do {                                                                             \
        float xsv = biasc;                                                           \
        xsv = fmaf((SX)[0], w2c[0], xsv); xsv = fmaf((SX)[1], w2c[1], xsv);          \
        xsv = fmaf((SX)[2], w2c[2], xsv); xsv = fmaf((SX)[3], w2c[3], xsv);          \
        xsv = fmaf((SX)[4], w2c[4], xsv); xsv = fmaf((SX)[5], w2c[5], xsv);          \
        xsv = fmaf((SX)[6], w2c[6], xsv); xsv = fmaf((SX)[7], w2c[7], xsv);          \
        float cv = cb + win0 * cw0 + win1 * cw1 + win2 * cw2 + xsv * cw3;            \
        win0 = win1; win1 = win2; win2 = xsv;                                        \
        xcv = silu_f(cv);                                                            \
        float acc = bdt;                                                             \
        acc = fmaf((SA)[0], wr[0], acc);  acc = fmaf((SA)[1], wr[1], acc);           \
        acc = fmaf((SA)[2], wr[2], acc);  acc = fmaf((SA)[3], wr[3], acc);           \
        acc = fmaf((SA)[4], wr[4], acc);  acc = fmaf((SA)[5], wr[5], acc);           \
        acc = fmaf((SA)[6], wr[6], acc);  acc = fmaf((SA)[7], wr[7], acc);           \
        acc = fmaf((SA)[8], wr[8], acc);  acc = fmaf((SA)[9], wr[9], acc);           \
        acc = fmaf((SA)[10], wr[10], acc); acc = fmaf((SA)[11], wr[11], acc);        \
        acc = fmaf((SA)[12], wr[12], acc); acc = fmaf((SA)[13], wr[13], acc);        \
        acc = fmaf((SA)[14], wr[14], acc); acc = fmaf((SA)[15], wr[15], acc);        \
        float dtv = (acc > 20.f) ? acc : __logf(1.f + __expf(acc));                  \
        S += dtv;                                                                    \
        float sv = dtv * xcv;                                                        \
        if (fast) {                                                                  \
            float E1 = __expf(dtv * An0);                                            \
            float E2 = E1 * E1, E3 = E2 * E1, E4 = E2 * E2;                          \
            float E5 = E4 * E1, E6 = E4 * E2, E7 = E4 * E3, E8 = E4 * E4;            \
            float E9 = E8 * E1, E10 = E8 * E2, E11 = E8 * E3, E12 = E8 * E4;         \
            float E13 = E8 * E5, E14 = E8 * E6, E15 = E8 * E7, E16 = E8 * E8;        \
            h[0] = fmaf(h[0], E1, sv * (SB)[0]);   h[1] = fmaf(h[1], E2, sv * (SB)[1]); \
            h[2] = fmaf(h[2], E3, sv * (SB)[2]);   h[3] = fmaf(h[3], E4, sv * (SB)[3]); \
            h[4] = fmaf(h[4], E5, sv * (SB)[4]);   h[5] = fmaf(h[5], E6, sv * (SB)[5]); \
            h[6] = fmaf(h[6], E7, sv * (SB)[6]);   h[7] = fmaf(h[7], E8, sv * (SB)[7]); \
            h[8] = fmaf(h[8], E9, sv * (SB)[8]);   h[9] = fmaf(h[9], E10, sv * (SB)[9]); \
            h[10] = fmaf(h[10], E11, sv * (SB)[10]); h[11] = fmaf(h[11], E12, sv * (SB)[11]); \
            h[12] = fmaf(h[12], E13, sv * (SB)[12]); h[13] = fmaf(h[13], E14, sv * (SB)[13]); \
            h[14] = fmaf(h[14], E15, sv * (SB)[14]); h[15] = fmaf(h[15], E16, sv * (SB)[15]); \
        } else {                                                                     \
            _Pragma("unroll")                                                        \
            for (int n = 0; n < NST; ++n) {                                          \
                float Ann = -__expf(A_log[d * NST + n]);                             \
                h[n] = fmaf(h[n], __expf(dtv * Ann), sv * (SB)[n]);                  \
            }                                                                        \
        }                                                                            \
    } while (0)

__global__ void __launch_bounds__(512, 4) k_scan(
    const float* __restrict__ x, const float* __restrict__ ws, const float* __restrict__ conv_b,
    const float* __restrict__ proj_g, const float* __restrict__ A_log,
    const float* __restrict__ dtw, const float* __restrict__ dtb,
    const float* __restrict__ Dvec, const float* __restrict__ silu_z,
    const int* __restrict__ flags, float* __restrict__ y_g) {
    __shared__ float h1_s[256 * 17];
    const int b = blockIdx.x >> 1, dgrp = blockIdx.x & 1;
    const int tid = threadIdx.x, half = tid >> 8, dl = tid & 255;
    const int d = dgrp * 256 + dl;
    const float* W2 = ws + W2_OFF;
    const float* b2 = ws + B2_OFF;
    const float* cwT = ws + CWT_OFF;
    const float* proj_b = proj_g + (size_t)b * SEQ * 48;
    const float* x_b = x + (size_t)b * SEQ * 8;

    float w2c[8];
#pragma unroll
    for (int i = 0; i < 8; ++i) w2c[i] = W2[i * 1024 + d];
    float biasc = b2[d];
    float cw0 = cwT[d], cw1 = cwT[512 + d], cw2 = cwT[1024 + d], cw3 = cwT[1536 + d];
    float cb = conv_b[d];
    float wr[DTRANK];
#pragma unroll
    for (int r = 0; r < DTRANK; ++r) wr[r] = dtw[r * DI + d];
    float bdt = dtb[d];
    float An0 = -__expf(A_log[d * NST]);
    const bool fast = flags[0] != 0;
    float h[NST];
#pragma unroll
    for (int n = 0; n < NST; ++n) h[n] = 0.f;
    float S = 0.f, xcv = 0.f;
    const int tstart = half * 50;

    float win0 = 0.f, win1 = 0.f, win2 = 0.f;
    for (int tt = tstart - 3; tt < tstart; ++tt) {
        float v = 0.f;
        if (tt >= 0) {
            const float4* xr = (const float4*)(x_b + tt * 8);
            float4 xa = xr[0], xb4 = xr[1];
            v = biasc + xa.x * w2c[0] + xa.y * w2c[1] + xa.z * w2c[2] + xa.w * w2c[3] +
                xb4.x * w2c[4] + xb4.y * w2c[5] + xb4.z * w2c[6] + xb4.w * w2c[7];
        }
        win0 = win1; win1 = win2; win2 = v;
    }

    int poff = rfl(tstart * 192);
    int xoff = rfl(tstart * 32);
    sf16 a0, a1, b0, b1;
    sf8 ax, bx;
    SL2(a0, a1, proj_b, poff, poff + 64);
    SLX(ax, x_b, xoff);
    SL_WAIT();
    for (int it = 0; it < 25; ++it) {
        int p1 = poff + 192, x1 = xoff + 32;
        SL2(b0, b1, proj_b, p1, p1 + 64);
        SLX(bx, x_b, x1);
        SCAN_STEP(a0, a1, ax);
        SL_WAIT();
        int p2 = (it < 24) ? poff + 384 : p1;
        int x2 = (it < 24) ? xoff + 64 : x1;
        SL2(a0, a1, proj_b, p2, p2 + 64);
        SLX(ax, x_b, x2);
        SCAN_STEP(b0, b1, bx);
        SL_WAIT();
        poff += 384;
        xoff += 64;
    }

    if (half == 0) {
#pragma unroll
        for (int n = 0; n < NST; ++n) h1_s[dl * 17 + n] = h[n];
    }
    __syncthreads();
    if (half == 1) {
        sf16 cC;
        SLC(cC, proj_b, (SEQ - 1) * 192 + 128);
        SL_WAIT();
        float yv = Dvec[d] * xcv;
        if (fast) {
            float G1 = __expf(S * An0);
            float G2 = G1 * G1, G3 = G2 * G1, G4 = G2 * G2;
            float G5 = G4 * G1, G6 = G4 * G2, G7 = G4 * G3, G8 = G4 * G4;
            float G9 = G8 * G1, G10 = G8 * G2, G11 = G8 * G3, G12 = G8 * G4;
            float G13 = G8 * G5, G14 = G8 * G6, G15 = G8 * G7, G16 = G8 * G8;
            float Gs[NST] = {G1, G2, G3, G4, G5, G6, G7, G8,
                             G9, G10, G11, G12, G13, G14, G15, G16};
#pragma unroll
            for (int n = 0; n < NST; ++n) {
                float hf = fmaf(h1_s[dl * 17 + n], Gs[n], h[n]);
                yv = fmaf(hf, cC[n], yv);
            }
        } else {
#pragma unroll
            for (int n = 0; n < NST; ++n) {
                float Ann = -__expf(A_log[d * NST + n]);
                float hf = fmaf(h1_s[dl * 17 + n], __expf(S * Ann), h[n]);
                yv = fmaf(hf, cC[n], yv);
            }
        }
        y_g[(size_t)b * DI + d] = yv * silu_z[(size_t)b * DI + d];
    }
}

// flow matvec (transposed weights, b128 row reads) + 3-layer decoder.
__global__ void __launch_bounds__(512, 2) k_flowdec(
    const float* __restrict__ x, const float* __restrict__ y_g,
    const float* __restrict__ mowt, const float* __restrict__ dec_in_w,
    const float* __restrict__ dec_in_b, const float* __restrict__ dec_flow_w,
    const float* __restrict__ dec_dt_w, const float* __restrict__ dec_dt_b,
    const float* __restrict__ dec_A_log, const float* __restrict__ dec_D,
    const float* __restrict__ dec_out_w, const float* __restrict__ dec_out_b,
    const int* __restrict__ flags, float* __restrict__ out) {
    __shared__ __align__(16) float y_s[DI];
    __shared__ __align__(16) float pf_s[48];
    __shared__ float red_s[DMODEL];
    __shared__ float flow_s[DMODEL];
    __shared__ float bbox_s[4];
    __shared__ float dred_s[8][4];
    const int b = blockIdx.x, tid = threadIdx.x, d = tid;
    const int lane = tid & 63, wv = tid >> 6;
    const bool dfast = flags[1] != 0;
    y_s[d] = y_g[(size_t)b * DI + d];
    if (tid < 4) bbox_s[tid] = x[(size_t)(b * SEQ + SEQ - 1) * 8 + tid];
    __syncthreads();
    {
        int j = tid >> 1, p = tid & 1;
        const float* wrow = mowt + (size_t)j * 512 + p * 256;
        const float* yrow = &y_s[p * 256];
        float fa = 0.f;
#pragma unroll 4
        for (int i = 0; i < 64; ++i) {
            float4 wq = *(const float4*)&wrow[4 * i];
            float4 yq = *(const float4*)&yrow[4 * i];
            fa += wq.x * yq.x + wq.y * yq.y + wq.z * yq.z + wq.w * yq.w;
        }
        if (p == 1) red_s[j] = fa;
        __syncthreads();
        if (p == 0) flow_s[j] = fa + red_s[j];
    }
    float h[NST];
#pragma unroll
    for (int n = 0; n < NST; ++n) h[n] = 0.f;
    __syncthreads();
    for (int L = 0; L < NLAYERS; ++L) {
        float epre = dec_in_b[L * 1024 + d];
        float rpre = dec_in_b[L * 1024 + 512 + d];
#pragma unroll
        for (int i = 0; i < 4; ++i) {
            float bx = bbox_s[i];
            epre += bx * dec_in_w[(L * 4 + i) * 1024 + d];
            rpre += bx * dec_in_w[(L * 4 + i) * 1024 + 512 + d];
        }
        float e = silu_f(epre);
        float fl4[4];
#pragma unroll
        for (int k = 0; k < 4; ++k) fl4[k] = flow_s[lane + 64 * k];
        float pj[6];
#pragma unroll
        for (int jj = 0; jj < 6; ++jj) {
            float a = 0.f;
#pragma unroll
            for (int k = 0; k < 4; ++k)
                a += fl4[k] * dec_flow_w[L * DMODEL * 48 + (lane + 64 * k) * 48 + wv * 6 + jj];
            pj[jj] = wave64_sum(a);
        }
        if (lane == 63) {
#pragma unroll
            for (int jj = 0; jj < 6; ++jj) pf_s[wv * 6 + jj] = pj[jj];
        }
        __syncthreads();
        float4 p0 = *(const float4*)&pf_s[0];
        float4 p1 = *(const float4*)&pf_s[4];
        float4 p2 = *(const float4*)&pf_s[8];
        float4 p3 = *(const float4*)&pf_s[12];
        float dtd = dec_dt_b[L * DID + d];
        dtd += p0.x * dec_dt_w[(L * 16 + 0) * DID + d] + p0.y * dec_dt_w[(L * 16 + 1) * DID + d] +
               p0.z * dec_dt_w[(L * 16 + 2) * DID + d] + p0.w * dec_dt_w[(L * 16 + 3) * DID + d];
        dtd += p1.x * dec_dt_w[(L * 16 + 4) * DID + d] + p1.y * dec_dt_w[(L * 16 + 5) * DID + d] +
               p1.z * dec_dt_w[(L * 16 + 6) * DID + d] + p1.w * dec_dt_w[(L * 16 + 7) * DID + d];
        dtd += p2.x * dec_dt_w[(L * 16 + 8) * DID + d] + p2.y * dec_dt_w[(L * 16 + 9) * DID + d] +
               p2.z * dec_dt_w[(L * 16 + 10) * DID + d] + p2.w * dec_dt_w[(L * 16 + 11) * DID + d];
        dtd += p3.x * dec_dt_w[(L * 16 + 12) * DID + d] + p3.y * dec_dt_w[(L * 16 + 13) * DID + d] +
               p3.z * dec_dt_w[(L * 16 + 14) * DID + d] + p3.w * dec_dt_w[(L * 16 + 15) * DID + d];
        dtd = (dtd > 20.f) ? dtd : __logf(1.f + __expf(dtd));
        float4 B0 = *(const float4*)&pf_s[16];
        float4 B1 = *(const float4*)&pf_s[20];
        float4 B2 = *(const float4*)&pf_s[24];
        float4 B3 = *(const float4*)&pf_s[28];
        float4 C0 = *(const float4*)&pf_s[32];
        float4 C1 = *(const float4*)&pf_s[36];
        float4 C2 = *(const float4*)&pf_s[40];
        float4 C3 = *(const float4*)&pf_s[44];
        float Bv[NST] = {B0.x, B0.y, B0.z, B0.w, B1.x, B1.y, B1.z, B1.w,
                         B2.x, B2.y, B2.z, B2.w, B3.x, B3.y, B3.z, B3.w};
        float Cv[NST] = {C0.x, C0.y, C0.z, C0.w, C1.x, C1.y, C1.z, C1.w,
                         C2.x, C2.y, C2.z, C2.w, C3.x, C3.y, C3.z, C3.w};
        float yd = 0.f;
        if (dfast) {
            float Ad0 = -__expf(dec_A_log[(L * DID + d) * NST]);
            float E1 = __expf(dtd * Ad0);
            float E2 = E1 * E1, E3 = E2 * E1, E4 = E2 * E2;
            float E5 = E4 * E1, E6 = E4 * E2, E7 = E4 * E3, E8 = E4 * E4;
            float E9 = E8 * E1, E10 = E8 * E2, E11 = E8 * E3, E12 = E8 * E4;
            float E13 = E8 * E5, E14 = E8 * E6, E15 = E8 * E7, E16 = E8 * E8;
            float Es[NST] = {E1, E2, E3, E4, E5, E6, E7, E8,
                             E9, E10, E11, E12, E13, E14, E15, E16};
#pragma unroll
            for (int n = 0; n < NST; ++n) {
                h[n] = fmaf(h[n], Es[n], e * (dtd * Bv[n]));
                yd += h[n] * Cv[n];
            }
        } else {
#pragma unroll
            for (int n = 0; n < NST; ++n) {
                float Adn = -__expf(dec_A_log[(L * DID + d) * NST + n]);
                h[n] = fmaf(h[n], __expf(dtd * Adn), e * (dtd * Bv[n]));
                yd += h[n] * Cv[n];
            }
        }
        yd += dec_D[L * DID + d] * e;
        yd *= silu_f(rpre);
#pragma unroll
        for (int jo = 0; jo < 4; ++jo) {
            float v = wave64_sum(yd * dec_out_w[(L * DID + d) * 4 + jo]);
            if (lane == 63) dred_s[wv][jo] = v;
        }
        __syncthreads();
        if (tid < 4) {
            float a2 = dec_out_b[L * 4 + tid];
#pragma unroll
            for (int w = 0; w < 8; ++w) a2 += dred_s[w][tid];
            bbox_s[tid] = a2;
            if (L == NLAYERS - 1) out[b * 4 + tid] = a2;
        }
        __syncthreads();
    }
}

extern "C" void kernel_launch(void* const* d_in, const int* in_sizes, int n_in,
                              void* d_out, int out_size, void* d_ws, size_t ws_size,
                              hipStream_t stream) {
    const float* x          = (const float*)d_in[0];
    const float* W_embed    = (const float*)d_in[1];
    const float* b_embed    = (const float*)d_in[2];
    const float* m_in_w     = (const float*)d_in[3];
    const float* m_conv_w   = (const float*)d_in[4];
    const float* m_conv_b   = (const float*)d_in[5];
    const float* m_xproj_w  = (const float*)d_in[6];
    const float* m_dtproj_w = (const float*)d_in[7];
    const float* m_dtproj_b = (const float*)d_in[8];
    const float* m_A_log    = (const float*)d_in[9];
    const float* m_D        = (const float*)d_in[10];
    const float* m_out_w    = (const float*)d_in[11];
    const float* dec_in_w   = (const float*)d_in[12];
    const float* dec_in_b   = (const float*)d_in[13];
    const float* dec_flow_w = (const float*)d_in[14];
    const float* dec_dt_w   = (const float*)d_in[15];
    const float* dec_dt_b   = (const float*)d_in[16];
    const float* dec_A_log  = (const float*)d_in[17];
    const float* dec_D      = (const float*)d_in[18];
    const float* dec_out_w  = (const float*)d_in[19];
    const float* dec_out_b  = (const float*)d_in[20];

    float* ws = (float*)d_ws;
    int* flags = (int*)(ws + FLAG_OFF);
    float* proj_g = ws + PROJ_OFF;
    float* siluz = ws + SILUZ_OFF;
    float* y_g = ws + Y_OFF;
    float* mowt = ws + MOWT_OFF;

    k_prep<<<621, 256, 0, stream>>>(W_embed, b_embed, m_in_w, m_xproj_w, m_conv_w,
                                    m_A_log, dec_A_log, m_out_w, ws, flags);
    k_convproj<<<BATCH * 2, 512, 0, stream>>>(x, ws, m_conv_b, ws + W2_OFF, proj_g, siluz);
    k_scan<<<BATCH * 2, 512, 0, stream>>>(x, ws, m_conv_b, proj_g, m_A_log, m_dtproj_w,
                                          m_dtproj_b, m_D, siluz, flags, y_g);
    k_flowdec<<<BATCH, 512, 0, stream>>>(x, y_g, mowt, dec_in_w, dec_in_b, dec_flow_w,
                                         dec_dt_w, dec_dt_b, dec_A_log, dec_D, dec_out_w,
                                         dec_out_b, flags, (float*)d_out);
}